// Round 7
// baseline (755.932 us; speedup 1.0000x reference)
//
#include <hip/hip_runtime.h>
#include <hip/hip_bf16.h>
#include <cstdint>
#include <cstddef>

#define B_   128
#define NCH  64
#define T_   30720
#define EPSF 1e-12f
#define THRF 0.5f

typedef float  f32x4 __attribute__((ext_vector_type(4)));
typedef short  s16x8 __attribute__((ext_vector_type(8)));
typedef unsigned short u16;

static __device__ __forceinline__ short bf16s(float f) {
    return (short)__builtin_bit_cast(u16, __float2bfloat16(f));
}

// ---------------------------------------------------------------------------
// Stage 1, wave-specialized, LDS-free, barrier-free.
// Per (batch, T-chunk) block of 4 waves:
//   waves 0,1 (COPY):   channels w*32..w*32+31. t-outer sweep; per pass one
//     1 KB fully-contiguous wave-row: load f32x4 -> NT store to out_x ->
//     fp32 ssum. Their store-retirement stalls are harmless (BW regulator).
//   waves 2,3 (GRAM):   sweep full chunk in K-steps of 32; load the four
//     16-channel fragment groups straight from global (L2-hot: the copy
//     waves pull the same lines in the same sliding window), cvt->bf16,
//     5 MFMA each (upper triangle split 5/5), NO stores in the loop.
// In-order vmcnt retirement never couples compute loads to copy stores
// (different waves). Epilogue: compute waves write their own P fragments
// (+symmetric mirrors); copy waves shfl-reduce and write S. No syncthreads.
// bf16 Gram: corr error <= ~4e-3, 40x under the 0.108 absmax threshold.
// ---------------------------------------------------------------------------
__global__ __launch_bounds__(256, 3) void corr_stage1(
    const float* __restrict__ x, float* __restrict__ out_x,
    float* __restrict__ P, float* __restrict__ S,
    int split, int Tc)
{
    const int tid  = threadIdx.x;
    const int lane = tid & 63;
    const int w    = tid >> 6;          // wave 0..3

    const int bid = blockIdx.x;
    const int b   = bid / split;
    const int c   = bid - b * split;

    const size_t base = (size_t)b * ((size_t)NCH * T_) + (size_t)c * Tc;

    if (w < 2) {
        // ================= COPY + S waves =================
        const int ch0 = w * 32;
        float ssum[32];
        #pragma unroll
        for (int i = 0; i < 32; ++i) ssum[i] = 0.f;

        const int nkt = Tc >> 8;        // 256-float t-blocks
        const float* xb = x     + base + (size_t)ch0 * T_ + (size_t)(lane * 4);
        float*       ob = out_x + base + (size_t)ch0 * T_ + (size_t)(lane * 4);

        for (int kt = 0; kt < nkt; ++kt) {
            const int toff = kt * 256;
            #pragma unroll
            for (int ch = 0; ch < 32; ++ch) {
                const size_t o = (size_t)ch * T_ + toff;
                const f32x4 v = *reinterpret_cast<const f32x4*>(xb + o);
                __builtin_nontemporal_store(v, reinterpret_cast<f32x4*>(ob + o));
                ssum[ch] += ((v.x + v.y) + (v.z + v.w));
            }
        }
        #pragma unroll
        for (int ch = 0; ch < 32; ++ch) {
            float v = ssum[ch];
            v += __shfl_xor(v, 1,  64);
            v += __shfl_xor(v, 2,  64);
            v += __shfl_xor(v, 4,  64);
            v += __shfl_xor(v, 8,  64);
            v += __shfl_xor(v, 16, 64);
            v += __shfl_xor(v, 32, 64);
            if (lane == 0) S[(size_t)bid * NCH + ch0 + ch] = v;
        }
    } else {
        // ================= GRAM waves =================
        const int cw = w - 2;           // 0 or 1
        const int cc = lane & 15;       // fragment row within 16-ch group
        const int g  = lane >> 4;       // k-group: lane's 8 t-samples

        const float* xw = x + base + (size_t)(g * 8);
        const int NK = Tc >> 5;         // K-steps of 32 (even)

        f32x4 acc[5];
        #pragma unroll
        for (int f = 0; f < 5; ++f) acc[f] = (f32x4)(0.f);

        f32x4 L0[4], H0[4], L1[4], H1[4];

        auto ISSUE = [&](int s, f32x4* L, f32x4* H) {
            const int toff = s * 32;
            #pragma unroll
            for (int i = 0; i < 4; ++i) {
                const float* p = xw + (size_t)(i * 16 + cc) * T_ + toff;
                L[i] = *reinterpret_cast<const f32x4*>(p);
                H[i] = *reinterpret_cast<const f32x4*>(p + 4);
            }
        };
        auto CONSUME = [&](f32x4* L, f32x4* H) {
            s16x8 A[4];
            #pragma unroll
            for (int i = 0; i < 4; ++i) {
                A[i][0] = bf16s(L[i].x); A[i][1] = bf16s(L[i].y);
                A[i][2] = bf16s(L[i].z); A[i][3] = bf16s(L[i].w);
                A[i][4] = bf16s(H[i].x); A[i][5] = bf16s(H[i].y);
                A[i][6] = bf16s(H[i].z); A[i][7] = bf16s(H[i].w);
            }
            if (cw == 0) {
                acc[0] = __builtin_amdgcn_mfma_f32_16x16x32_bf16(A[0], A[0], acc[0], 0, 0, 0);
                acc[1] = __builtin_amdgcn_mfma_f32_16x16x32_bf16(A[0], A[1], acc[1], 0, 0, 0);
                acc[2] = __builtin_amdgcn_mfma_f32_16x16x32_bf16(A[0], A[2], acc[2], 0, 0, 0);
                acc[3] = __builtin_amdgcn_mfma_f32_16x16x32_bf16(A[0], A[3], acc[3], 0, 0, 0);
                acc[4] = __builtin_amdgcn_mfma_f32_16x16x32_bf16(A[1], A[1], acc[4], 0, 0, 0);
            } else {
                acc[0] = __builtin_amdgcn_mfma_f32_16x16x32_bf16(A[1], A[2], acc[0], 0, 0, 0);
                acc[1] = __builtin_amdgcn_mfma_f32_16x16x32_bf16(A[1], A[3], acc[1], 0, 0, 0);
                acc[2] = __builtin_amdgcn_mfma_f32_16x16x32_bf16(A[2], A[2], acc[2], 0, 0, 0);
                acc[3] = __builtin_amdgcn_mfma_f32_16x16x32_bf16(A[2], A[3], acc[3], 0, 0, 0);
                acc[4] = __builtin_amdgcn_mfma_f32_16x16x32_bf16(A[3], A[3], acc[4], 0, 0, 0);
            }
        };

        ISSUE(0, L0, H0);
        ISSUE(1, L1, H1);
        for (int s = 0; s < NK; s += 2) {
            CONSUME(L0, H0);
            if (s + 2 < NK) ISSUE(s + 2, L0, H0);
            CONSUME(L1, H1);
            if (s + 3 < NK) ISSUE(s + 3, L1, H1);
        }

        // ---- write this wave's fragments (+ mirrors); D layout:
        //      col = lane&15, row = (lane>>4)*4 + reg ----
        float* Pc = P + ((size_t)bid << 12);
        const int row = (lane >> 4) << 2;
        const int col = lane & 15;
        auto WR = [&](int i, int j, const f32x4& a) {
            #pragma unroll
            for (int reg = 0; reg < 4; ++reg) {
                const float v = a[reg];
                Pc[(i * 16 + row + reg) * 64 + (j * 16 + col)] = v;
                if (i != j)
                    Pc[(j * 16 + col) * 64 + (i * 16 + row + reg)] = v;
            }
        };
        if (cw == 0) {
            WR(0, 0, acc[0]); WR(0, 1, acc[1]); WR(0, 2, acc[2]);
            WR(0, 3, acc[3]); WR(1, 1, acc[4]);
        } else {
            WR(1, 2, acc[0]); WR(1, 3, acc[1]); WR(2, 2, acc[2]);
            WR(2, 3, acc[3]); WR(3, 3, acc[4]);
        }
    }
}

// ---------------------------------------------------------------------------
// Stage 2: combine chunk partials -> corr -> threshold -> adj
// ---------------------------------------------------------------------------
__global__ __launch_bounds__(256) void corr_stage2(
    const float* __restrict__ P, const float* __restrict__ S,
    float* __restrict__ adj, int split)
{
    const int idx = blockIdx.x * 256 + threadIdx.x;   // < 128*4096
    const int b  = idx >> 12;
    const int nm = idx & 4095;
    const int n  = nm >> 6;
    const int m  = nm & 63;

    float G = 0.f, Gnn = 0.f, Gmm = 0.f, Sn = 0.f, Sm = 0.f;
    for (int c = 0; c < split; ++c) {
        const float* Pc = P + ((size_t)(b * split + c) << 12);
        const float* Sc = S + (size_t)(b * split + c) * NCH;
        G   += Pc[nm];
        Gnn += Pc[n * 65];
        Gmm += Pc[m * 65];
        Sn  += Sc[n];
        Sm  += Sc[m];
    }
    const float invT = 1.0f / (float)T_;
    const float cov  = G   - Sn * Sm * invT;
    const float vn   = Gnn - Sn * Sn * invT;
    const float vm   = Gmm - Sm * Sm * invT;
    const float den  = sqrtf(vn) * sqrtf(vm) + EPSF;
    float corr = cov / den;
    if (n == m) corr = 0.f;
    adj[idx] = (fabsf(corr) >= THRF) ? corr : 0.f;
}

// ---------------------------------------------------------------------------
extern "C" void kernel_launch(void* const* d_in, const int* in_sizes, int n_in,
                              void* d_out, int out_size, void* d_ws, size_t ws_size,
                              hipStream_t stream)
{
    const float* x   = (const float*)d_in[0];
    float* out   = (float*)d_out;
    float* adj   = out;                                  // 128*64*64
    float* out_x = out + (size_t)B_ * NCH * NCH;         // passthrough x

    // split: Tc must be divisible by 256. 6 -> grid 768 = 256 CU x 3 exactly.
    int split = 6;
    while (split > 3 &&
           (size_t)B_ * split * (4096 + NCH) * sizeof(float) > ws_size)
        split >>= 1;

    float* P = (float*)d_ws;
    float* S = P + (size_t)B_ * split * 4096;
    const int Tc = T_ / split;

    corr_stage1<<<dim3(B_ * split), dim3(256), 0, stream>>>(x, out_x, P, S, split, Tc);
    corr_stage2<<<dim3((B_ * 4096) / 256), dim3(256), 0, stream>>>(P, S, adj, split);
}

// Round 8
// 453.265 us; speedup vs baseline: 1.6677x; 1.6677x over previous
//
#include <hip/hip_runtime.h>
#include <hip/hip_bf16.h>
#include <cstdint>
#include <cstddef>

#define B_   128
#define NCH  64
#define T_   30720
#define EPSF 1e-12f
#define THRF 0.5f

typedef float  f32x4 __attribute__((ext_vector_type(4)));
typedef short  s16x8 __attribute__((ext_vector_type(8)));
typedef unsigned short u16;

#define AS1 __attribute__((address_space(1)))
#define AS3 __attribute__((address_space(3)))

static __device__ __forceinline__ short bf16s(float f) {
    return (short)__builtin_bit_cast(u16, __float2bfloat16(f));
}

// ---------------------------------------------------------------------------
// Stage 1: DMA-staged streaming Gram + fused copy.
// Per (batch, T-chunk) block: 256 thr / 4 waves, LDS [2][64ch][128t] f32.
// Per 128-t tile:
//   1. issue 32x global_load_lds dwordx4 DMA for the NEXT tile (8/wave,
//      1 KB each, no VGPRs -> 32 KB of reads in flight per block; this is
//      the latency-BW fix: register-staged loads max out at ~2-4 KB/CU).
//   2. copy-out current tile: ds_read -> contiguous 1 KB/instr NT stores
//      to out_x + per-channel fp32 sums (S).
//   3. cvt f32->bf16 in regs, 16 MFMA/wave (full 64x64 Gram; symmetric so
//      any D-layout transpose is harmless). bf16 corr err ~4e-3 << 0.108.
//   4. one barrier; its vmcnt(0) drain retires DMA + NT stores under the
//      whole compute phase. Buffers flip.
// LDS swizzle: granule (16B) index XOR (row&7), applied by PRE-SWIZZLING the
// DMA's per-lane GLOBAL source (dest must stay lane-linear, m104/m173);
// all LDS reads apply the same XOR -> <=2-way conflicts everywhere.
// ---------------------------------------------------------------------------
__global__ __launch_bounds__(256) void corr_stage1(
    const float* __restrict__ x, float* __restrict__ out_x,
    float* __restrict__ P, float* __restrict__ S,
    int split, int Tc)
{
    __shared__ __align__(16) float lds[2][NCH * 128];   // 2 x 32 KB

    const int tid  = threadIdx.x;
    const int lane = tid & 63;
    const int w    = tid >> 6;          // wave 0..3

    const int bid = blockIdx.x;
    const int b   = bid / split;
    const int c   = bid - b * split;

    const size_t base = (size_t)b * ((size_t)NCH * T_) + (size_t)c * Tc;
    const float* xw = x + base;
    float*       ow = out_x + base;

    const int NT = Tc >> 7;             // 128-t tiles per chunk

    // DMA / copy lane mapping: instr k (0..31) covers rows 2k, 2k+1;
    // lane: row = 2k + (lane>>5), granule slot = lane&31 (16 B granules).
    const int sg = lane & 31;
    const int hi = lane >> 5;

    // fragment mapping
    const int fr = lane & 15;           // fragment row within 16-ch block
    const int g8 = lane >> 4;           // k-subgroup 0..3
    const int fs = fr & 7;              // row swizzle

    f32x4 acc[4];
    #pragma unroll
    for (int cb = 0; cb < 4; ++cb) acc[cb] = (f32x4)(0.f);
    float csum[8];
    #pragma unroll
    for (int kk = 0; kk < 8; ++kk) csum[kk] = 0.f;

    auto dma = [&](int tile, int buf) {
        #pragma unroll
        for (int kk = 0; kk < 8; ++kk) {
            const int k  = w * 8 + kk;
            const int ch = 2 * k + hi;
            const int gg = sg ^ (ch & 7);               // pre-swizzled source
            const float* src = xw + (size_t)ch * T_ + (size_t)(tile * 128 + gg * 4);
            float* dst = &lds[buf][k * 256];            // wave-uniform, linear
            __builtin_amdgcn_global_load_lds((const AS1 void*)src,
                                             (AS3 void*)dst, 16, 0, 0);
        }
    };

    dma(0, 0);
    asm volatile("s_waitcnt vmcnt(0)" ::: "memory");
    __syncthreads();

    for (int t = 0; t < NT; ++t) {
        const int cur = t & 1;
        if (t + 1 < NT) dma(t + 1, cur ^ 1);

        // ---- copy-out: contiguous 1 KB NT stores + channel sums ----
        #pragma unroll
        for (int kk = 0; kk < 8; ++kk) {
            const int k   = w * 8 + kk;
            const int row = 2 * k + hi;
            const f32x4 v = *reinterpret_cast<const f32x4*>(
                &lds[cur][row * 128 + ((sg ^ (row & 7)) << 2)]);
            float* q = ow + (size_t)row * T_ + (size_t)(t * 128 + sg * 4);
            __builtin_nontemporal_store(v, reinterpret_cast<f32x4*>(q));
            csum[kk] += ((v.x + v.y) + (v.z + v.w));
        }

        // ---- Gram: 4 K-steps of 32 ----
        #pragma unroll
        for (int ks = 0; ks < 4; ++ks) {
            const int g0 = ks * 8 + g8 * 2;
            const f32x4 alo = *reinterpret_cast<const f32x4*>(
                &lds[cur][(w * 16 + fr) * 128 + ((g0 ^ fs) << 2)]);
            const f32x4 ahi = *reinterpret_cast<const f32x4*>(
                &lds[cur][(w * 16 + fr) * 128 + (((g0 + 1) ^ fs) << 2)]);
            s16x8 Af;
            Af[0] = bf16s(alo.x); Af[1] = bf16s(alo.y);
            Af[2] = bf16s(alo.z); Af[3] = bf16s(alo.w);
            Af[4] = bf16s(ahi.x); Af[5] = bf16s(ahi.y);
            Af[6] = bf16s(ahi.z); Af[7] = bf16s(ahi.w);
            #pragma unroll
            for (int cb = 0; cb < 4; ++cb) {
                s16x8 Bf;
                if (cb == w) {
                    Bf = Af;
                } else {
                    const f32x4 blo = *reinterpret_cast<const f32x4*>(
                        &lds[cur][(cb * 16 + fr) * 128 + ((g0 ^ fs) << 2)]);
                    const f32x4 bhi = *reinterpret_cast<const f32x4*>(
                        &lds[cur][(cb * 16 + fr) * 128 + (((g0 + 1) ^ fs) << 2)]);
                    Bf[0] = bf16s(blo.x); Bf[1] = bf16s(blo.y);
                    Bf[2] = bf16s(blo.z); Bf[3] = bf16s(blo.w);
                    Bf[4] = bf16s(bhi.x); Bf[5] = bf16s(bhi.y);
                    Bf[6] = bf16s(bhi.z); Bf[7] = bf16s(bhi.w);
                }
                acc[cb] = __builtin_amdgcn_mfma_f32_16x16x32_bf16(Af, Bf, acc[cb], 0, 0, 0);
            }
        }

        asm volatile("s_waitcnt vmcnt(0)" ::: "memory");  // DMA(t+1) + stores done
        __syncthreads();
    }

    // ---- S: reduce csum across the 32 lanes sharing (w,kk,hi) ----
    #pragma unroll
    for (int kk = 0; kk < 8; ++kk) {
        float v = csum[kk];
        v += __shfl_xor(v, 1,  64);
        v += __shfl_xor(v, 2,  64);
        v += __shfl_xor(v, 4,  64);
        v += __shfl_xor(v, 8,  64);
        v += __shfl_xor(v, 16, 64);
        if ((lane & 31) == 0) {
            const int row = 2 * (w * 8 + kk) + hi;
            S[(size_t)bid * NCH + row] = v;
        }
    }

    // ---- P: wave w owns rows w*16..w*16+15, all 4 col blocks.
    //      D layout col=lane&15, row=(lane>>4)*4+reg (transpose-safe: symmetric).
    float* Pc = P + ((size_t)bid << 12);
    const int prow = (lane >> 4) << 2;
    const int pcol = lane & 15;
    #pragma unroll
    for (int cb = 0; cb < 4; ++cb)
        #pragma unroll
        for (int reg = 0; reg < 4; ++reg)
            Pc[(w * 16 + prow + reg) * 64 + cb * 16 + pcol] = acc[cb][reg];
}

// ---------------------------------------------------------------------------
// Stage 2: combine chunk partials -> corr -> threshold -> adj
// ---------------------------------------------------------------------------
__global__ __launch_bounds__(256) void corr_stage2(
    const float* __restrict__ P, const float* __restrict__ S,
    float* __restrict__ adj, int split)
{
    const int idx = blockIdx.x * 256 + threadIdx.x;   // < 128*4096
    const int b  = idx >> 12;
    const int nm = idx & 4095;
    const int n  = nm >> 6;
    const int m  = nm & 63;

    float G = 0.f, Gnn = 0.f, Gmm = 0.f, Sn = 0.f, Sm = 0.f;
    for (int c = 0; c < split; ++c) {
        const float* Pc = P + ((size_t)(b * split + c) << 12);
        const float* Sc = S + (size_t)(b * split + c) * NCH;
        G   += Pc[nm];
        Gnn += Pc[n * 65];
        Gmm += Pc[m * 65];
        Sn  += Sc[n];
        Sm  += Sc[m];
    }
    const float invT = 1.0f / (float)T_;
    const float cov  = G   - Sn * Sm * invT;
    const float vn   = Gnn - Sn * Sn * invT;
    const float vm   = Gmm - Sm * Sm * invT;
    const float den  = sqrtf(vn) * sqrtf(vm) + EPSF;
    float corr = cov / den;
    if (n == m) corr = 0.f;
    adj[idx] = (fabsf(corr) >= THRF) ? corr : 0.f;
}

// ---------------------------------------------------------------------------
extern "C" void kernel_launch(void* const* d_in, const int* in_sizes, int n_in,
                              void* d_out, int out_size, void* d_ws, size_t ws_size,
                              hipStream_t stream)
{
    const float* x   = (const float*)d_in[0];
    float* out   = (float*)d_out;
    float* adj   = out;                                  // 128*64*64
    float* out_x = out + (size_t)B_ * NCH * NCH;         // passthrough x

    // split=4 -> 512 blocks = 256 CU x 2 exactly (64 KB LDS -> 2 blocks/CU).
    int split = 4;
    while (split > 1 &&
           (size_t)B_ * split * (4096 + NCH) * sizeof(float) > ws_size)
        split >>= 1;

    float* P = (float*)d_ws;
    float* S = P + (size_t)B_ * split * 4096;
    const int Tc = T_ / split;

    corr_stage1<<<dim3(B_ * split), dim3(256), 0, stream>>>(x, out_x, P, S, split, Tc);
    corr_stage2<<<dim3((B_ * 4096) / 256), dim3(256), 0, stream>>>(P, S, adj, split);
}

// Round 9
// 453.156 us; speedup vs baseline: 1.6681x; 1.0002x over previous
//
#include <hip/hip_runtime.h>
#include <hip/hip_bf16.h>
#include <cstdint>
#include <cstddef>

#define B_   128
#define NCH  64
#define T_   30720
#define EPSF 1e-12f
#define THRF 0.5f

typedef float  f32x4 __attribute__((ext_vector_type(4)));
typedef short  s16x8 __attribute__((ext_vector_type(8)));
typedef unsigned short u16;

#define AS1 __attribute__((address_space(1)))
#define AS3 __attribute__((address_space(3)))

static __device__ __forceinline__ short bf16s(float f) {
    return (short)__builtin_bit_cast(u16, __float2bfloat16(f));
}

// ---------------------------------------------------------------------------
// Stage 1: DMA-staged streaming Gram + fused copy (R8 structure) with
// COUNTED vmcnt + raw s_barrier instead of __syncthreads (T4):
//   per wave per tile the VMEM queue is [ST_prev(<=8), DMA_next(8), ST_cur(8)]
//   (in-order retirement, m135). s_waitcnt vmcnt(8) guarantees DMA_next has
//   landed while the current tile's 8 NT stores stay in flight -- store
//   retirement gets a full tile of slack instead of a per-tile drain.
// Everything else identical to R8 (verified correct, absmax 0):
//   - [2][64ch][128t] f32 LDS, global_load_lds dwordx4 staging (32 KB of
//     reads in flight per block -- the latency-BW fix)
//   - copy-out: ds_read -> contiguous 1 KB/instr NT stores + fp32 csums
//   - Gram: cvt f32->bf16 in regs, 16 MFMA/wave, full 64x64 (symmetric,
//     transpose-immune); bf16 corr err ~4e-3 << 0.108 threshold
//   - LDS swizzle via pre-swizzled DMA global source (dest lane-linear)
// ---------------------------------------------------------------------------
__global__ __launch_bounds__(256) void corr_stage1(
    const float* __restrict__ x, float* __restrict__ out_x,
    float* __restrict__ P, float* __restrict__ S,
    int split, int Tc)
{
    __shared__ __align__(16) float lds[2][NCH * 128];   // 2 x 32 KB

    const int tid  = threadIdx.x;
    const int lane = tid & 63;
    const int w    = tid >> 6;          // wave 0..3

    const int bid = blockIdx.x;
    const int b   = bid / split;
    const int c   = bid - b * split;

    const size_t base = (size_t)b * ((size_t)NCH * T_) + (size_t)c * Tc;
    const float* xw = x + base;
    float*       ow = out_x + base;

    const int NT = Tc >> 7;             // 128-t tiles per chunk

    // DMA / copy lane mapping: instr k (0..31) covers rows 2k, 2k+1;
    // lane: row = 2k + (lane>>5), granule slot = lane&31 (16 B granules).
    const int sg = lane & 31;
    const int hi = lane >> 5;

    // fragment mapping
    const int fr = lane & 15;           // fragment row within 16-ch block
    const int g8 = lane >> 4;           // k-subgroup 0..3
    const int fs = fr & 7;              // row swizzle

    f32x4 acc[4];
    #pragma unroll
    for (int cb = 0; cb < 4; ++cb) acc[cb] = (f32x4)(0.f);
    float csum[8];
    #pragma unroll
    for (int kk = 0; kk < 8; ++kk) csum[kk] = 0.f;

    auto dma = [&](int tile, int buf) {
        #pragma unroll
        for (int kk = 0; kk < 8; ++kk) {
            const int k  = w * 8 + kk;
            const int ch = 2 * k + hi;
            const int gg = sg ^ (ch & 7);               // pre-swizzled source
            const float* src = xw + (size_t)ch * T_ + (size_t)(tile * 128 + gg * 4);
            float* dst = &lds[buf][k * 256];            // wave-uniform, linear
            __builtin_amdgcn_global_load_lds((const AS1 void*)src,
                                             (AS3 void*)dst, 16, 0, 0);
        }
    };

    dma(0, 0);
    asm volatile("s_waitcnt vmcnt(0)" ::: "memory");
    __builtin_amdgcn_s_barrier();
    __builtin_amdgcn_sched_barrier(0);

    for (int t = 0; t < NT; ++t) {
        const int cur = t & 1;
        if (t + 1 < NT) dma(t + 1, cur ^ 1);

        // ---- copy-out: contiguous 1 KB NT stores + channel sums ----
        #pragma unroll
        for (int kk = 0; kk < 8; ++kk) {
            const int k   = w * 8 + kk;
            const int row = 2 * k + hi;
            const f32x4 v = *reinterpret_cast<const f32x4*>(
                &lds[cur][row * 128 + ((sg ^ (row & 7)) << 2)]);
            float* q = ow + (size_t)row * T_ + (size_t)(t * 128 + sg * 4);
            __builtin_nontemporal_store(v, reinterpret_cast<f32x4*>(q));
            csum[kk] += ((v.x + v.y) + (v.z + v.w));
        }

        // ---- Gram: 4 K-steps of 32 ----
        #pragma unroll
        for (int ks = 0; ks < 4; ++ks) {
            const int g0 = ks * 8 + g8 * 2;
            const f32x4 alo = *reinterpret_cast<const f32x4*>(
                &lds[cur][(w * 16 + fr) * 128 + ((g0 ^ fs) << 2)]);
            const f32x4 ahi = *reinterpret_cast<const f32x4*>(
                &lds[cur][(w * 16 + fr) * 128 + (((g0 + 1) ^ fs) << 2)]);
            s16x8 Af;
            Af[0] = bf16s(alo.x); Af[1] = bf16s(alo.y);
            Af[2] = bf16s(alo.z); Af[3] = bf16s(alo.w);
            Af[4] = bf16s(ahi.x); Af[5] = bf16s(ahi.y);
            Af[6] = bf16s(ahi.z); Af[7] = bf16s(ahi.w);
            #pragma unroll
            for (int cb = 0; cb < 4; ++cb) {
                s16x8 Bf;
                if (cb == w) {
                    Bf = Af;
                } else {
                    const f32x4 blo = *reinterpret_cast<const f32x4*>(
                        &lds[cur][(cb * 16 + fr) * 128 + ((g0 ^ fs) << 2)]);
                    const f32x4 bhi = *reinterpret_cast<const f32x4*>(
                        &lds[cur][(cb * 16 + fr) * 128 + (((g0 + 1) ^ fs) << 2)]);
                    Bf[0] = bf16s(blo.x); Bf[1] = bf16s(blo.y);
                    Bf[2] = bf16s(blo.z); Bf[3] = bf16s(blo.w);
                    Bf[4] = bf16s(bhi.x); Bf[5] = bf16s(bhi.y);
                    Bf[6] = bf16s(bhi.z); Bf[7] = bf16s(bhi.w);
                }
                acc[cb] = __builtin_amdgcn_mfma_f32_16x16x32_bf16(Af, Bf, acc[cb], 0, 0, 0);
            }
        }

        // counted wait: own DMA(t+1) retired (oldest in queue); own NT
        // stores of THIS tile may remain in flight (<=8) across the barrier.
        asm volatile("s_waitcnt vmcnt(8)" ::: "memory");
        __builtin_amdgcn_s_barrier();
        __builtin_amdgcn_sched_barrier(0);
    }

    // ---- S: reduce csum across the 32 lanes sharing (w,kk,hi) ----
    #pragma unroll
    for (int kk = 0; kk < 8; ++kk) {
        float v = csum[kk];
        v += __shfl_xor(v, 1,  64);
        v += __shfl_xor(v, 2,  64);
        v += __shfl_xor(v, 4,  64);
        v += __shfl_xor(v, 8,  64);
        v += __shfl_xor(v, 16, 64);
        if ((lane & 31) == 0) {
            const int row = 2 * (w * 8 + kk) + hi;
            S[(size_t)bid * NCH + row] = v;
        }
    }

    // ---- P: wave w owns rows w*16..w*16+15, all 4 col blocks.
    //      D layout col=lane&15, row=(lane>>4)*4+reg (transpose-safe: symmetric).
    float* Pc = P + ((size_t)bid << 12);
    const int prow = (lane >> 4) << 2;
    const int pcol = lane & 15;
    #pragma unroll
    for (int cb = 0; cb < 4; ++cb)
        #pragma unroll
        for (int reg = 0; reg < 4; ++reg)
            Pc[(w * 16 + prow + reg) * 64 + cb * 16 + pcol] = acc[cb][reg];
}

// ---------------------------------------------------------------------------
// Stage 2: combine chunk partials -> corr -> threshold -> adj
// ---------------------------------------------------------------------------
__global__ __launch_bounds__(256) void corr_stage2(
    const float* __restrict__ P, const float* __restrict__ S,
    float* __restrict__ adj, int split)
{
    const int idx = blockIdx.x * 256 + threadIdx.x;   // < 128*4096
    const int b  = idx >> 12;
    const int nm = idx & 4095;
    const int n  = nm >> 6;
    const int m  = nm & 63;

    float G = 0.f, Gnn = 0.f, Gmm = 0.f, Sn = 0.f, Sm = 0.f;
    for (int c = 0; c < split; ++c) {
        const float* Pc = P + ((size_t)(b * split + c) << 12);
        const float* Sc = S + (size_t)(b * split + c) * NCH;
        G   += Pc[nm];
        Gnn += Pc[n * 65];
        Gmm += Pc[m * 65];
        Sn  += Sc[n];
        Sm  += Sc[m];
    }
    const float invT = 1.0f / (float)T_;
    const float cov  = G   - Sn * Sm * invT;
    const float vn   = Gnn - Sn * Sn * invT;
    const float vm   = Gmm - Sm * Sm * invT;
    const float den  = sqrtf(vn) * sqrtf(vm) + EPSF;
    float corr = cov / den;
    if (n == m) corr = 0.f;
    adj[idx] = (fabsf(corr) >= THRF) ? corr : 0.f;
}

// ---------------------------------------------------------------------------
extern "C" void kernel_launch(void* const* d_in, const int* in_sizes, int n_in,
                              void* d_out, int out_size, void* d_ws, size_t ws_size,
                              hipStream_t stream)
{
    const float* x   = (const float*)d_in[0];
    float* out   = (float*)d_out;
    float* adj   = out;                                  // 128*64*64
    float* out_x = out + (size_t)B_ * NCH * NCH;         // passthrough x

    // split=4 -> 512 blocks = 256 CU x 2 exactly (64 KB LDS -> 2 blocks/CU).
    int split = 4;
    while (split > 1 &&
           (size_t)B_ * split * (4096 + NCH) * sizeof(float) > ws_size)
        split >>= 1;

    float* P = (float*)d_ws;
    float* S = P + (size_t)B_ * split * 4096;
    const int Tc = T_ / split;

    corr_stage1<<<dim3(B_ * split), dim3(256), 0, stream>>>(x, out_x, P, S, split, Tc);
    corr_stage2<<<dim3((B_ * 4096) / 256), dim3(256), 0, stream>>>(P, S, adj, split);
}